// Round 7
// baseline (373.050 us; speedup 1.0000x reference)
//
#include <hip/hip_runtime.h>
#include <hip/hip_bf16.h>

#define B_ 8
#define L_ 256
#define D_ 128
#define H_ 4
#define NB_ 2
#define ROWS (B_*L_)            // 2048
#define NEGV (-4294967295.0f)   // -(2^32)+1 as float
#define TSTRIDE 260             // padded 257 (per-head stride in DQT/W tables)
#define RSTRIDE (H_*TSTRIDE)    // 1040 floats per (b,q) row

typedef __hip_bfloat16 bf16;

__device__ __forceinline__ float us2f(unsigned short u){ return __uint_as_float(((unsigned)u)<<16); }
__device__ __forceinline__ unsigned short f2us(float f){ bf16 h=__float2bfloat16(f); return *(unsigned short*)&h; }
__device__ __forceinline__ float b2f(bf16 x){ return __bfloat162float(x); }

struct WPtrs { const float* p[10]; };   // Wq0,Wk0,Wv0,W1_0,W2_0, Wq1,Wk1,Wv1,W1_1,W2_1

// one-time prep: embed seqs | weights fp32->bf16 | timeK/timeV fp32->bf16 tables
__global__ __launch_bounds__(256) void k_prep(const float* __restrict__ item_emb,
        const int* __restrict__ log_seqs, float* __restrict__ seqs,
        WPtrs wp, unsigned short* __restrict__ wsW,
        const float* __restrict__ timeK, const float* __restrict__ timeV,
        unsigned short* __restrict__ tmK, unsigned short* __restrict__ tmV) {
    int tid = threadIdx.x, bid = blockIdx.x;
    if (bid < 256) {
        int gi = bid*256 + tid;          // float4 index, 65536 total
        int r = gi >> 5, c4 = gi & 31;
        int id = log_seqs[r];
        float4 v = ((const float4*)item_emb)[id*32 + c4];
        float sc = (id==0) ? 0.0f : 11.3137085f;   // sqrt(128)
        v.x*=sc; v.y*=sc; v.z*=sc; v.w*=sc;
        ((float4*)seqs)[gi] = v;
    } else if (bid < 416) {
        int m = (bid-256) >> 4, ch = (bid-256) & 15;
        float4 v = ((const float4*)wp.p[m])[ch*256 + tid];
        ushort4 o; o.x=f2us(v.x); o.y=f2us(v.y); o.z=f2us(v.z); o.w=f2us(v.w);
        ((ushort4*)(wsW + (size_t)m*16384))[ch*256 + tid] = o;
    } else {
        int gi = (bid-416)*256 + tid;    // float4 idx over 2x 8224
        if (gi < 8224) {
            float4 v = ((const float4*)timeK)[gi];
            ushort4 o; o.x=f2us(v.x); o.y=f2us(v.y); o.z=f2us(v.z); o.w=f2us(v.w);
            ((ushort4*)tmK)[gi] = o;
        } else if (gi < 16448) {
            int gj = gi - 8224;
            float4 v = ((const float4*)timeV)[gj];
            ushort4 o; o.x=f2us(v.x); o.y=f2us(v.y); o.z=f2us(v.z); o.w=f2us(v.w);
            ((ushort4*)tmV)[gj] = o;
        }
    }
}

// stage one 128x128 bf16 matrix (32KB) global -> LDS
__device__ __forceinline__ void stage_w(const unsigned short* __restrict__ Wg,
                                        unsigned short* sW, int tid){
    const uint4* src = (const uint4*)Wg;
    uint4* dst = (uint4*)sW;
    #pragma unroll
    for (int j=0;j<8;j++) dst[j*256+tid] = src[j*256+tid];
}

// LayerNorm of 8 LDS rows; thread t: row t>>5, 4 elems strided 32.
__device__ __forceinline__ void ln_rows(const float* sA, float* sOut,
        const float* __restrict__ g, const float* __restrict__ b,
        float* qin_out, int r0, int tid){
    int r = tid>>5, l = tid&31;
    const float* x = sA + r*128;
    float x0=x[l], x1=x[l+32], x2=x[l+64], x3=x[l+96];
    float s = x0+x1+x2+x3;
    #pragma unroll
    for (int o=16;o;o>>=1) s += __shfl_xor(s,o,64);
    float m = s*(1.f/128.f);
    float d0=x0-m,d1=x1-m,d2=x2-m,d3=x3-m;
    float v = d0*d0+d1*d1+d2*d2+d3*d3;
    #pragma unroll
    for (int o=16;o;o>>=1) v += __shfl_xor(v,o,64);
    float rstd = rsqrtf(v*(1.f/128.f)+1e-8f);
    float y0=d0*rstd*g[l]+b[l];
    float y1=d1*rstd*g[l+32]+b[l+32];
    float y2=d2*rstd*g[l+64]+b[l+64];
    float y3=d3*rstd*g[l+96]+b[l+96];
    float* o_ = sOut + r*128;
    o_[l]=y0; o_[l+32]=y1; o_[l+64]=y2; o_[l+96]=y3;
    if (qin_out){
        float* q = qin_out + (size_t)(r0+r)*128;
        q[l]=y0; q[l+32]=y1; q[l+64]=y2; q[l+96]=y3;
    }
}

// 2-row x 2-col register tile over K=128 from LDS
__device__ __forceinline__ void gemm2x2(const float* A, const unsigned short* sW,
        int ra, int rb, int c0, float* acc){
    float a00=0,a01=0,a10=0,a11=0;
    const float* Ar = A + ra*128;
    const float* Br = A + rb*128;
    #pragma unroll 8
    for (int k=0;k<128;k++){
        ushort2 wp = *(const ushort2*)(sW + k*128 + c0);
        float w0=us2f(wp.x), w1=us2f(wp.y);
        float x0=Ar[k], x1=Br[k];
        a00=fmaf(x0,w0,a00); a01=fmaf(x0,w1,a01);
        a10=fmaf(x1,w0,a10); a11=fmaf(x1,w1,a11);
    }
    acc[0]=a00; acc[1]=a01; acc[2]=a10; acc[3]=a11;
}

// 1-row x 2-col tile
__device__ __forceinline__ void gemm1x2(const float* Ar, const unsigned short* sW,
        int c0, float& o0, float& o1){
    float a0=0,a1=0;
    #pragma unroll 8
    for (int k=0;k<128;k++){
        ushort2 wp = *(const ushort2*)(sW + k*128 + c0);
        float x = Ar[k];
        a0 = fmaf(x, us2f(wp.x), a0);
        a1 = fmaf(x, us2f(wp.y), a1);
    }
    o0=a0; o1=a1;
}

// QKV: grid 768 = {Q,K,V} x 256 row-groups of 8. Q-blocks compute LN1 + write qin.
__global__ __launch_bounds__(256) void k_qkv(const float* __restrict__ seqs,
        const unsigned short* __restrict__ Wqb, const unsigned short* __restrict__ Wkb,
        const unsigned short* __restrict__ Wvb,
        const float* __restrict__ bq, const float* __restrict__ bk, const float* __restrict__ bv,
        const float* __restrict__ ln1g, const float* __restrict__ ln1b,
        const float* __restrict__ posK, const float* __restrict__ posV,
        float* __restrict__ qin, bf16* __restrict__ Qo, bf16* __restrict__ Ko,
        bf16* __restrict__ Vo){
    __shared__ unsigned short sW[16384];
    __shared__ float sA[1024], sAq[1024];
    int tid = threadIdx.x;
    int m = blockIdx.x >> 8;            // 0=Q, 1=K, 2=V
    int rg = blockIdx.x & 255;
    int r0 = rg*8;
    ((float4*)sA)[tid] = ((const float4*)(seqs + (size_t)r0*128))[tid];
    const unsigned short* Wg = (m==0)?Wqb:(m==1)?Wkb:Wvb;
    stage_w(Wg, sW, tid);
    __syncthreads();
    const float* src = sA;
    if (m==0){
        ln_rows(sA, sAq, ln1g, ln1b, qin, r0, tid);
        src = sAq;
        __syncthreads();
    }
    int cp = tid & 63, rp = tid >> 6;
    int c0 = 2*cp, ra = 2*rp, rb = ra+1;
    float acc[4];
    gemm2x2(src, sW, ra, rb, c0, acc);
    if (m==0){
        float b0v = bq[c0], b1v = bq[c0+1];
        ushort2 s0; s0.x=f2us(acc[0]+b0v); s0.y=f2us(acc[1]+b1v);
        ushort2 s1; s1.x=f2us(acc[2]+b0v); s1.y=f2us(acc[3]+b1v);
        *(ushort2*)((unsigned short*)Qo + (size_t)(r0+ra)*128 + c0) = s0;
        *(ushort2*)((unsigned short*)Qo + (size_t)(r0+rb)*128 + c0) = s1;
    } else {
        const float* bb = (m==1)?bk:bv;
        const float* pp = (m==1)?posK:posV;
        bf16* Oo = (m==1)?Ko:Vo;
        int qa = (r0+ra)&(L_-1), qb2 = (r0+rb)&(L_-1);
        float b0v = bb[c0], b1v = bb[c0+1];
        ushort2 s0; s0.x=f2us(acc[0]+b0v+pp[qa*128+c0]);  s0.y=f2us(acc[1]+b1v+pp[qa*128+c0+1]);
        ushort2 s1; s1.x=f2us(acc[2]+b0v+pp[qb2*128+c0]); s1.y=f2us(acc[3]+b1v+pp[qb2*128+c0+1]);
        *(ushort2*)((unsigned short*)Oo + (size_t)(r0+ra)*128 + c0) = s0;
        *(ushort2*)((unsigned short*)Oo + (size_t)(r0+rb)*128 + c0) = s1;
    }
}

// DQT[b,q][h][t] = (Q[b,q]/sqrt(32))_h . timeK_h[t]; grid = 2048 blocks (one per b,q)
__global__ __launch_bounds__(256) void k_dqt(const bf16* __restrict__ Q,
        const unsigned short* __restrict__ tmK, float* __restrict__ DQT){
    __shared__ float sq[128];
    int tid = threadIdx.x, bq = blockIdx.x;
    if (tid < 128) sq[tid] = b2f(Q[(size_t)bq*128+tid]) * 0.17677669529663687f;
    __syncthreads();
    for (int t = tid; t < 257; t += 256){
        const uint4* T4 = (const uint4*)(tmK + (size_t)t*128);
        float acc[4] = {0.f,0.f,0.f,0.f};
        #pragma unroll
        for (int c=0;c<16;c++){
            uint4 tv = T4[c];
            const unsigned short* tu = (const unsigned short*)&tv;
            const float* qq = sq + c*8;
            acc[c>>2] += qq[0]*us2f(tu[0]) + qq[1]*us2f(tu[1])
                       + qq[2]*us2f(tu[2]) + qq[3]*us2f(tu[3])
                       + qq[4]*us2f(tu[4]) + qq[5]*us2f(tu[5])
                       + qq[6]*us2f(tu[6]) + qq[7]*us2f(tu[7]);
        }
        #pragma unroll
        for (int h=0;h<H_;h++)
            DQT[(size_t)bq*RSTRIDE + h*TSTRIDE + t] = acc[h];
    }
}

// attention core: one block per (b, q-pair {p,255-p}).
// scores = Qs.K' + DQT[tm]; softmax; histogram W[h][t] = sum A; PV from V' only.
// writes pre = PV + qin (pre-LN2) and W.
__global__ __launch_bounds__(256) void k_attn(
        const bf16* __restrict__ Q, const bf16* __restrict__ Kb,
        const bf16* __restrict__ Vb, const float* __restrict__ qin,
        const int* __restrict__ log_seqs, const int* __restrict__ tmat,
        const float* __restrict__ DQT, float* __restrict__ Wout,
        float* __restrict__ pre){
    __shared__ __align__(16) float sQ[2][D_];
    __shared__ float sS[2][H_][L_];
    __shared__ int   sTM[2][L_];
    __shared__ float sPr[2][8][D_];
    __shared__ float sDQ[2][H_][TSTRIDE];
    __shared__ float sWH[2][H_][TSTRIDE];
    int tid = threadIdx.x;
    int b = blockIdx.x >> 7, p = blockIdx.x & 127;
    int q1 = p, q2 = L_-1-p;
    int b0 = b*L_;
    int r1 = b0+q1, r2 = b0+q2;
    bool pad1 = log_seqs[r1]==0, pad2 = log_seqs[r2]==0;
    const float scale = 0.17677669529663687f;
    if (tid < 128) sQ[0][tid] = b2f(Q[(size_t)r1*128+tid])*scale;
    else           sQ[1][tid-128] = b2f(Q[(size_t)r2*128+(tid-128)])*scale;
    int k = tid;
    int tmv1 = tmat[(size_t)r1*L_+k], tmv2 = tmat[(size_t)r2*L_+k];
    sTM[0][k]=tmv1; sTM[1][k]=tmv2;
    // stage DQT rows + zero histogram
    float* sDQf = (float*)sDQ; float* sWHf = (float*)sWH;
    for (int j=tid; j<2*RSTRIDE; j+=256){
        int i = j >= RSTRIDE;
        int rest = j - i*RSTRIDE;
        sDQf[j] = DQT[(size_t)(i? r2:r1)*RSTRIDE + rest];
        sWHf[j] = 0.f;
    }
    __syncthreads();

    // phase 1: scores = Qs.K' + DQT[h][tm]
    {
        const uint4* K4 = (const uint4*)(Kb + (size_t)(b0+k)*128);
        #pragma unroll
        for (int i=0;i<2;i++){
            int qq = i? q2:q1; bool pad = i? pad2:pad1;
            int tm = i? tmv2:tmv1;
            bool act = (k<=qq) && !pad;
            float acc[4] = {0.f,0.f,0.f,0.f};
            if (act){
                const float4* Q4 = (const float4*)sQ[i];
                #pragma unroll
                for (int c=0;c<16;c++){
                    uint4 kv = K4[c];
                    float4 qa = Q4[2*c], qb = Q4[2*c+1];
                    const unsigned short* ku = (const unsigned short*)&kv;
                    acc[c>>2] += qa.x*us2f(ku[0]) + qa.y*us2f(ku[1])
                               + qa.z*us2f(ku[2]) + qa.w*us2f(ku[3])
                               + qb.x*us2f(ku[4]) + qb.y*us2f(ku[5])
                               + qb.z*us2f(ku[6]) + qb.w*us2f(ku[7]);
                }
            }
            #pragma unroll
            for (int h=0;h<H_;h++)
                sS[i][h][k] = act ? acc[h] + sDQ[i][h][tm] : NEGV;
        }
    }
    __syncthreads();

    // phase 2: softmax; wave h -> head h, both queries
    {
        int h = tid>>6, lane = tid&63;
        #pragma unroll
        for (int i=0;i<2;i++){
            float v0=sS[i][h][lane], v1=sS[i][h][lane+64],
                  v2=sS[i][h][lane+128], v3=sS[i][h][lane+192];
            float m = fmaxf(fmaxf(v0,v1),fmaxf(v2,v3));
            #pragma unroll
            for (int o=32;o;o>>=1) m = fmaxf(m,__shfl_xor(m,o,64));
            float e0=__expf(v0-m), e1=__expf(v1-m), e2=__expf(v2-m), e3=__expf(v3-m);
            float ss=e0+e1+e2+e3;
            #pragma unroll
            for (int o=32;o;o>>=1) ss += __shfl_xor(ss,o,64);
            float inv = 1.f/ss;
            sS[i][h][lane]=e0*inv;     sS[i][h][lane+64]=e1*inv;
            sS[i][h][lane+128]=e2*inv; sS[i][h][lane+192]=e3*inv;
        }
    }
    __syncthreads();

    // histogram: W[i][h][tm[k]] += A[i][h][k]  (exact reassociation of timeV term)
    #pragma unroll
    for (int i=0;i<2;i++){
        int tm = i? tmv2:tmv1;
        #pragma unroll
        for (int h=0;h<H_;h++) atomicAdd(&sWH[i][h][tm], sS[i][h][k]);
    }

    // phase 3: PV from V' only (sequential rows, no gather)
    {
        int dq = tid&31, slice = tid>>5, h = dq>>3;
        #pragma unroll
        for (int i=0;i<2;i++){
            int qq = i? q2:q1; bool pad = i? pad2:pad1;
            int kend = pad? L_ : qq+1;
            int k0 = slice*32;
            int kmax = kend - k0; kmax = kmax<0?0:(kmax>32?32:kmax);
            float a0=0,a1=0,a2=0,a3=0;
            for (int kk=0;kk<kmax;kk++){
                int kx = k0+kk;
                float a = sS[i][h][kx];
                ushort4 v4 = ((const ushort4*)(Vb + (size_t)(b0+kx)*128))[dq];
                a0 = fmaf(a, us2f(v4.x), a0);
                a1 = fmaf(a, us2f(v4.y), a1);
                a2 = fmaf(a, us2f(v4.z), a2);
                a3 = fmaf(a, us2f(v4.w), a3);
            }
            ((float4*)sPr[i][slice])[dq] = make_float4(a0,a1,a2,a3);
        }
    }
    __syncthreads();   // also guarantees histogram atomics complete

    // epilogue: pre = PV + qin; write W
    {
        int i = tid>>7, l = tid&127;
        int rr = i? r2:r1;
        float v = qin[(size_t)rr*128 + l];
        #pragma unroll
        for (int sl=0;sl<8;sl++) v += sPr[i][sl][l];
        pre[(size_t)rr*128+l] = v;
    }
    for (int j=tid; j<2*RSTRIDE; j+=256){
        int i = j >= RSTRIDE;
        int rest = j - i*RSTRIDE;
        Wout[(size_t)(i? r2:r1)*RSTRIDE + rest] = sWHf[j];
    }
}

// TV matvec + residual + LN2 + FFN + mask; grid 512 x 4 rows
__global__ __launch_bounds__(256) void k_tvffn(const float* __restrict__ pre,
        const float* __restrict__ Wt, const unsigned short* __restrict__ tmV,
        const unsigned short* __restrict__ W1b, const unsigned short* __restrict__ W2b,
        const float* __restrict__ b1, const float* __restrict__ b2,
        const int* __restrict__ maskids,
        const float* __restrict__ ln2g, const float* __restrict__ ln2b,
        float* __restrict__ outseq){
    __shared__ unsigned short sW[16384];
    __shared__ float sA[512], sH[512];
    int tid=threadIdx.x; int r0=blockIdx.x*4;
    int rp=tid>>6, l=tid&63, c0=2*l, h=c0>>5;
    int r = r0+rp;
    stage_w(W1b, sW, tid);
    // TV: out[c] = pre[c] + sum_t W[r][h][t]*tmV[t][c]
    float o0 = pre[(size_t)r*128+c0], o1 = pre[(size_t)r*128+c0+1];
    {
        const float* Wr = Wt + (size_t)r*RSTRIDE + h*TSTRIDE;
        const unsigned short* tv = tmV + c0;
        for (int t=0;t<257;t++){
            float w = Wr[t];
            if (w != 0.f){
                ushort2 vv = *(const ushort2*)(tv + (size_t)t*128);
                o0 = fmaf(w, us2f(vv.x), o0);
                o1 = fmaf(w, us2f(vv.y), o1);
            }
        }
    }
    // LN2 (wave rp owns row rp; 64 lanes x 2 elems)
    {
        float s = o0+o1;
        #pragma unroll
        for (int o=32;o;o>>=1) s += __shfl_xor(s,o,64);
        float m = s*(1.f/128.f);
        float d0=o0-m, d1=o1-m;
        float v = d0*d0+d1*d1;
        #pragma unroll
        for (int o=32;o;o>>=1) v += __shfl_xor(v,o,64);
        float rstd = rsqrtf(v*(1.f/128.f)+1e-8f);
        sA[rp*128+c0]   = d0*rstd*ln2g[c0]+ln2b[c0];
        sA[rp*128+c0+1] = d1*rstd*ln2g[c0+1]+ln2b[c0+1];
    }
    __syncthreads();
    float h0,h1;
    gemm1x2(sA + rp*128, sW, c0, h0, h1);
    sH[rp*128+c0]   = fmaxf(h0+b1[c0],0.f);
    sH[rp*128+c0+1] = fmaxf(h1+b1[c0+1],0.f);
    __syncthreads();
    stage_w(W2b, sW, tid);
    __syncthreads();
    float f0,f1;
    gemm1x2(sH + rp*128, sW, c0, f0, f1);
    bool msk = maskids[r]==0;
    f0 = msk?0.f:(f0+b2[c0]  +sA[rp*128+c0]);
    f1 = msk?0.f:(f1+b2[c0+1]+sA[rp*128+c0+1]);
    outseq[(size_t)r*128 + c0]   = f0;
    outseq[(size_t)r*128 + c0+1] = f1;
}

// final LN + pos/neg logits: grid 256 x 8 rows
__global__ __launch_bounds__(256) void k_lnlogits(const float* __restrict__ x,
        const float* __restrict__ lnfg, const float* __restrict__ lnfb,
        const int* __restrict__ pos_seqs, const int* __restrict__ neg_seqs,
        const float* __restrict__ item_emb, float* __restrict__ outp){
    __shared__ float sA[1024], sH[1024];
    int tid=threadIdx.x; int r0=blockIdx.x*8;
    ((float4*)sA)[tid] = ((const float4*)(x + (size_t)r0*128))[tid];
    __syncthreads();
    ln_rows(sA, sH, lnfg, lnfb, nullptr, r0, tid);
    __syncthreads();
    int w = tid>>6, lane = tid&63;
    #pragma unroll
    for (int j=0;j<4;j++){
        int o = w*4 + j;                 // 16 = 8 rows x {pos,neg}
        int row = o>>1; int neg = o&1;
        int rg = r0 + row;
        int id = neg ? neg_seqs[rg] : pos_seqs[rg];
        const float* e = item_emb + (size_t)id*128;
        const float* fr = sH + row*128;
        float s = fr[lane]*e[lane] + fr[lane+64]*e[lane+64];
        #pragma unroll
        for (int oo=32;oo;oo>>=1) s += __shfl_xor(s,oo,64);
        if (lane==0) outp[(neg?ROWS:0) + rg] = s;
    }
}

extern "C" void kernel_launch(void* const* d_in, const int* in_sizes, int n_in,
                              void* d_out, int out_size, void* d_ws, size_t ws_size,
                              hipStream_t stream) {
    const int* log_seqs = (const int*)d_in[1];
    const int* tmat     = (const int*)d_in[2];
    const int* pos_seqs = (const int*)d_in[3];
    const int* neg_seqs = (const int*)d_in[4];
    const float* item_emb = (const float*)d_in[5];
    const float* posK  = (const float*)d_in[6];
    const float* posV  = (const float*)d_in[7];
    const float* timeK = (const float*)d_in[8];
    const float* timeV = (const float*)d_in[9];
    const float* ln1_g = (const float*)d_in[10];
    const float* ln1_b = (const float*)d_in[11];
    const float* Wq = (const float*)d_in[12];
    const float* bqv = (const float*)d_in[13];
    const float* Wk = (const float*)d_in[14];
    const float* bk = (const float*)d_in[15];
    const float* Wv = (const float*)d_in[16];
    const float* bv = (const float*)d_in[17];
    const float* ln2_g = (const float*)d_in[18];
    const float* ln2_b = (const float*)d_in[19];
    const float* W1 = (const float*)d_in[20];
    const float* b1 = (const float*)d_in[21];
    const float* W2 = (const float*)d_in[22];
    const float* b2 = (const float*)d_in[23];
    const float* lnf_g = (const float*)d_in[24];
    const float* lnf_b = (const float*)d_in[25];

    // ws (≈268MB available): fp32/bf16 buffers, generous spacing
    const int NE = ROWS * D_;       // 262144
    char* wsb = (char*)d_ws;
    float* s_seqs = (float*)(wsb + 0);                     // 1MB
    float* s_qin  = (float*)(wsb + (size_t)NE * 4);        // 1MB
    bf16*  s_Q    = (bf16*) (wsb + (size_t)NE * 8);        // 0.5MB
    bf16*  s_K    = (bf16*) (wsb + (size_t)NE * 8 + (size_t)NE * 2);
    bf16*  s_V    = (bf16*) (wsb + (size_t)NE * 8 + (size_t)NE * 4);
    unsigned short* wsW = (unsigned short*)(wsb + (size_t)NE * 14);  // 320KB
    unsigned short* tmK = (unsigned short*)(wsb + (size_t)NE * 14 + 327680);
    unsigned short* tmV = tmK + 32896;
    float* s_pre  = (float*)(wsb + (16u<<20));             // 1MB
    float* s_DQT  = (float*)(wsb + (20u<<20));             // 8.5MB
    float* s_W    = (float*)(wsb + (32u<<20));             // 8.5MB

    const int DD = D_*D_;   // 16384
    WPtrs wp;
    wp.p[0]=Wq;      wp.p[1]=Wk;      wp.p[2]=Wv;      wp.p[3]=W1;      wp.p[4]=W2;
    wp.p[5]=Wq+DD;   wp.p[6]=Wk+DD;   wp.p[7]=Wv+DD;   wp.p[8]=W1+DD;   wp.p[9]=W2+DD;

    k_prep<<<482, 256, 0, stream>>>(item_emb, log_seqs, s_seqs, wp, wsW,
                                    timeK, timeV, tmK, tmV);
    for (int i = 0; i < NB_; i++) {
        k_qkv<<<768, 256, 0, stream>>>(s_seqs, wsW+(5*i+0)*DD, wsW+(5*i+1)*DD, wsW+(5*i+2)*DD,
                bqv+i*D_, bk+i*D_, bv+i*D_, ln1_g+i*D_, ln1_b+i*D_, posK, posV,
                s_qin, s_Q, s_K, s_V);
        k_dqt<<<2048, 256, 0, stream>>>(s_Q, tmK, s_DQT);
        k_attn<<<1024, 256, 0, stream>>>(s_Q, s_K, s_V, s_qin, log_seqs, tmat,
                s_DQT, s_W, s_pre);
        k_tvffn<<<512, 256, 0, stream>>>(s_pre, s_W, tmV,
                wsW+(5*i+3)*DD, wsW+(5*i+4)*DD, b1+i*D_, b2+i*D_, log_seqs,
                ln2_g+i*D_, ln2_b+i*D_, s_seqs);
    }
    k_lnlogits<<<256, 256, 0, stream>>>(s_seqs, lnf_g, lnf_b, pos_seqs, neg_seqs,
                                        item_emb, (float*)d_out);
}